// Round 9
// baseline (183.341 us; speedup 1.0000x reference)
//
#include <hip/hip_runtime.h>
#include <hip/hip_bf16.h>
#include <math.h>

#define B 8
#define C 256
#define HEADS 8
#define D 32
#define NPIX 1024
#define OC 768
#define SCALE 0.17677669529663687f   // 1/sqrt(32)
#define LOG2E 1.4426950408889634f
#define QKSCALE (SCALE * LOG2E)      // folded into stored Q

#if __has_builtin(__builtin_amdgcn_exp2f)
#define EXP2(x) __builtin_amdgcn_exp2f(x)
#else
#define EXP2(x) exp2f(x)
#endif

typedef unsigned int uint;
typedef unsigned short u16;
typedef __attribute__((ext_vector_type(8))) short bf16x8;
typedef __attribute__((ext_vector_type(4))) float f32x4;

static __device__ inline u16 f2bf(float f) {   // RNE f32->bf16
  uint u = __float_as_uint(f);
  return (u16)((u + 0x7fffu + ((u >> 16) & 1u)) >> 16);
}
static __device__ inline float bf_lo(uint u) { return __uint_as_float(u << 16); }
static __device__ inline float bf_hi(uint u) { return __uint_as_float(u & 0xffff0000u); }

// ---------------------------------------------------------------------------
// P0: fused prep. Blocks [0,256): weights fp32->bf16 (wqkv then wout).
// Blocks [256,768): transpose-convert x[b][c][pix] -> XT[b][pix][c] bf16.
// ---------------------------------------------------------------------------
__global__ __launch_bounds__(256) void k_prep(
    const float* __restrict__ x, const float* __restrict__ wqkv,
    const float* __restrict__ wout,
    u16* __restrict__ WQ, u16* __restrict__ WO, u16* __restrict__ XT) {
  const int bid = blockIdx.x, t = threadIdx.x;
  __shared__ u16 tile[64][65];
  if (bid < 256) {
    const float* src;
    u16* dst;
    int base;
    if (bid < 192) { src = wqkv; dst = WQ; base = bid * 1024; }
    else           { src = wout; dst = WO; base = (bid - 192) * 1024; }
    float4 v = *(const float4*)(src + base + t * 4);
    uint2 pk = make_uint2((uint)f2bf(v.x) | ((uint)f2bf(v.y) << 16),
                          (uint)f2bf(v.z) | ((uint)f2bf(v.w) << 16));
    *(uint2*)(dst + base + t * 4) = pk;
    return;
  }
  const int id = bid - 256;
  const int pt = id & 15, ct = (id >> 4) & 3, b = id >> 6;
  {
    const int px = t & 63, cq = t >> 6;
    const float* xb = x + ((size_t)(b * C + ct * 64)) * NPIX + pt * 64;
#pragma unroll
    for (int m = 0; m < 16; ++m) {
      const int c = cq * 16 + m;
      tile[c][px] = f2bf(xb[(size_t)c * NPIX + px]);
    }
  }
  __syncthreads();
  {
    const int cc = t & 63, pq = t >> 6;
    u16* dst = XT + ((size_t)(b * NPIX + pt * 64)) * C + ct * 64;
#pragma unroll
    for (int m = 0; m < 16; ++m) {
      const int pix = pq * 16 + m;
      dst[(size_t)pix * C + cc] = tile[cc][pix];
    }
  }
}

// ---------------------------------------------------------------------------
// K1: QKV GEMM via MFMA. Q stored PRE-SCALED by QKSCALE (k_red compensates).
// Grid (12 o-blocks of 64, 8 pix-blocks of 128, 8 b), 4 waves.
// ---------------------------------------------------------------------------
__global__ __launch_bounds__(256) void k_qkv_mfma(
    const u16* __restrict__ XT, const u16* __restrict__ WQ,
    u16* __restrict__ Q, u16* __restrict__ Kk, u16* __restrict__ VT) {
  const int ob = blockIdx.x, pb = blockIdx.y, b = blockIdx.z;
  const int wv = threadIdx.x >> 6, lane = threadIdx.x & 63;
  const int quad = lane >> 4, l15 = lane & 15;
  const int part = ob >> 2;
  const int odl = (ob & 3) * 64 + wv * 16;
  const int hh = odl >> 5, d0 = odl & 31;
  const int bh = b * HEADS + hh;
  const int pix0 = pb * 128;

  const u16* arow = WQ + (size_t)(ob * 64 + wv * 16 + l15) * C;
  bf16x8 af[8];
#pragma unroll
  for (int kc = 0; kc < 8; ++kc)
    af[kc] = *(const bf16x8*)(arow + kc * 32 + quad * 8);

  const u16* xb = XT + (size_t)(b * NPIX + pix0) * C;
  f32x4 acc[8];
#pragma unroll
  for (int nt = 0; nt < 8; ++nt) acc[nt] = (f32x4){0.f, 0.f, 0.f, 0.f};

  for (int kc = 0; kc < 8; ++kc) {
#pragma unroll
    for (int nt = 0; nt < 8; ++nt) {
      bf16x8 bfr = *(const bf16x8*)(xb + (size_t)(nt * 16 + l15) * C +
                                    kc * 32 + quad * 8);
      acc[nt] = __builtin_amdgcn_mfma_f32_16x16x32_bf16(af[kc], bfr, acc[nt], 0, 0, 0);
    }
  }

  if (part < 2) {
    const float sc = (part == 0) ? (float)QKSCALE : 1.f;
    u16* dst = (part == 0 ? Q : Kk) + (size_t)bh * NPIX * D;
#pragma unroll
    for (int nt = 0; nt < 8; ++nt) {
      const int pix = pix0 + nt * 16 + l15;
      uint2 pk = make_uint2(
          (uint)f2bf(acc[nt][0] * sc) | ((uint)f2bf(acc[nt][1] * sc) << 16),
          (uint)f2bf(acc[nt][2] * sc) | ((uint)f2bf(acc[nt][3] * sc) << 16));
      *(uint2*)(dst + (size_t)pix * D + d0 + 4 * quad) = pk;
    }
  } else {
#pragma unroll
    for (int nt = 0; nt < 8; ++nt) {
      const int pix = pix0 + nt * 16 + l15;
#pragma unroll
      for (int r = 0; r < 4; ++r) {
        const int d = d0 + 4 * quad + r;
        VT[((size_t)bh * D + d) * NPIX + pix] = f2bf(acc[nt][r]);
      }
    }
  }
}

// ---------------------------------------------------------------------------
// R: fused reductions. Blocks [0,8): diag_vec[b] (Q is pre-scaled by QKSCALE,
// so multiply by 0.125/LOG2E to land at SCALE/8). Blocks [8,72): colsum[bh].
// ---------------------------------------------------------------------------
__global__ __launch_bounds__(256) void k_red(
    const uint* __restrict__ Q, const uint* __restrict__ Kk,
    const u16* __restrict__ VT, float* __restrict__ diagv,
    float* __restrict__ colsum) {
  const int bid = blockIdx.x, tid = threadIdx.x;
  __shared__ float red[256];
  if (bid < 8) {
    const int b = bid;
    const int hh = tid >> 5, dd = tid & 31;
    const uint* qb = Q + (size_t)(b * HEADS + hh) * NPIX * (D / 2);
    const uint* kb = Kk + (size_t)(b * HEADS + hh) * NPIX * (D / 2);
    float s = 0.f;
#pragma unroll 4
    for (int t = 0; t < 32; ++t) {
      uint qu = qb[t * 33 * (D / 2) + dd / 2];
      uint ku = kb[t * 33 * (D / 2) + dd / 2];
      float qv = (dd & 1) ? bf_hi(qu) : bf_lo(qu);
      float kv = (dd & 1) ? bf_hi(ku) : bf_lo(ku);
      s += qv * kv;
    }
    red[tid] = s;
    __syncthreads();
    if (tid < 32) {
      float v = 0.f;
#pragma unroll
      for (int h8 = 0; h8 < 8; ++h8) v += red[h8 * 32 + tid];
      diagv[b * 32 + tid] = v * (0.125f / LOG2E);
    }
  } else {
    const int bh = bid - 8;
    const int dd = tid >> 3, sl = tid & 7;
    const uint* row = (const uint*)(VT + ((size_t)bh * D + dd) * NPIX) + sl * 64;
    float s = 0.f;
#pragma unroll 8
    for (int j = 0; j < 64; ++j) {
      uint u = row[j];
      s += bf_lo(u) + bf_hi(u);
    }
    red[tid] = s;
    __syncthreads();
    if (tid < 32) {
      float v = 0.f;
#pragma unroll
      for (int g = 0; g < 8; ++g) v += red[tid * 8 + g];
      colsum[bh * D + tid] = v;
    }
  }
}

// ---------------------------------------------------------------------------
// K2: MFMA flash attention with split-j. Grid (32 qc, 64 bh), 4 waves:
// wave = (group g = wv>>1 of 16 q-rows, j-half jh = wv&1 of 512 j).
// No-max softmax => split-j merge is pure addition (no rescale).
// P goes through wave-private LDS as bf16 (direct A-frag readback).
// ---------------------------------------------------------------------------
__global__ __launch_bounds__(256, 8) void k_attn(
    const u16* __restrict__ Q, const u16* __restrict__ Kk,
    const u16* __restrict__ VT, const float* __restrict__ diagv,
    const float* __restrict__ colsum, u16* __restrict__ AOT) {
  const int qc = blockIdx.x;           // 0..31
  const int bh = blockIdx.y;           // 0..63
  const int b = bh >> 3, hh = bh & 7;
  const int wv = threadIdx.x >> 6, lane = threadIdx.x & 63;
  const int g = wv >> 1, jh = wv & 1;
  const int quad = lane >> 4, l15 = lane & 15;
  const int i0 = qc * 32 + g * 16;

  __shared__ u16 Pws_all[4][16 * 72];   // 9.2 KB, wave-private P (bf16)
  __shared__ float Om[2][544];          // jh=1 partial O per group
  __shared__ float Lm[2][16];           // jh=1 partial l per group
  u16* Pws = Pws_all[wv];

  const u16* Qb  = Q  + (size_t)bh * NPIX * D;
  const u16* Kb  = Kk + (size_t)bh * NPIX * D;
  const u16* VTb = VT + (size_t)bh * D * NPIX;

  bf16x8 qfrag = *(const bf16x8*)(Qb + (size_t)(i0 + l15) * D + quad * 8);

  f32x4 oacc[2];
  oacc[0] = (f32x4){0.f, 0.f, 0.f, 0.f};
  oacc[1] = (f32x4){0.f, 0.f, 0.f, 0.f};
  float lacc[4] = {};

  for (int it = 0; it < 8; ++it) {
    const int jb = jh * 512 + it * 64;
    // S = Q K^T (4 MFMA); scores arrive pre-scaled in log2 domain
    f32x4 st[4];
#pragma unroll
    for (int jt = 0; jt < 4; ++jt) {
      bf16x8 kfrag = *(const bf16x8*)(Kb + (size_t)(jb + jt * 16 + l15) * D + quad * 8);
      st[jt] = __builtin_amdgcn_mfma_f32_16x16x32_bf16(
          qfrag, kfrag, (f32x4){0.f, 0.f, 0.f, 0.f}, 0, 0, 0);
    }
    // exp + l-accumulate + P -> LDS as bf16 (C-layout write)
#pragma unroll
    for (int jt = 0; jt < 4; ++jt)
#pragma unroll
      for (int r = 0; r < 4; ++r) {
        float pv = EXP2(fminf(st[jt][r], 80.f));
        lacc[r] += pv;
        Pws[(quad * 4 + r) * 72 + jt * 16 + l15] = f2bf(pv);
      }
    __builtin_amdgcn_wave_barrier();
    // PV: A-frags read directly from LDS (b128), 4 MFMA
#pragma unroll
    for (int kt = 0; kt < 2; ++kt) {
      bf16x8 pfrag = *(const bf16x8*)(Pws + l15 * 72 + kt * 32 + quad * 8);
#pragma unroll
      for (int nt = 0; nt < 2; ++nt) {
        bf16x8 vfrag = *(const bf16x8*)(VTb + (size_t)(nt * 16 + l15) * NPIX +
                                        jb + kt * 32 + quad * 8);
        oacc[nt] = __builtin_amdgcn_mfma_f32_16x16x32_bf16(
            pfrag, vfrag, oacc[nt], 0, 0, 0);
      }
    }
    __builtin_amdgcn_wave_barrier();
  }

  // per-wave l reduce over the 16 j-classes
#pragma unroll
  for (int r = 0; r < 4; ++r) {
    float v = lacc[r];
    v += __shfl_xor(v, 1, 16);
    v += __shfl_xor(v, 2, 16);
    v += __shfl_xor(v, 4, 16);
    v += __shfl_xor(v, 8, 16);
    lacc[r] = v;
  }

  // split-j merge: jh=1 publishes partials; jh=0 combines + epilogue
  if (jh == 1) {
#pragma unroll
    for (int nt = 0; nt < 2; ++nt)
#pragma unroll
      for (int r = 0; r < 4; ++r)
        Om[g][(nt * 16 + l15) * 17 + quad * 4 + r] = oacc[nt][r];
    if (l15 == 0) {
#pragma unroll
      for (int r = 0; r < 4; ++r) Lm[g][quad * 4 + r] = lacc[r];
    }
  }
  __syncthreads();
  if (jh == 0) {
    float linv[4];
#pragma unroll
    for (int r = 0; r < 4; ++r)
      linv[r] = 1.f / (lacc[r] + Lm[g][quad * 4 + r]);
    const bool do_diag = (i0 < 32);
#pragma unroll
    for (int nt = 0; nt < 2; ++nt) {
      const int dch = hh * 32 + nt * 16 + l15;
      float cs = do_diag ? colsum[bh * D + nt * 16 + l15] : 0.f;
#pragma unroll
      for (int r = 0; r < 4; ++r) {
        const int irow = i0 + quad * 4 + r;
        float o = (oacc[nt][r] + Om[g][(nt * 16 + l15) * 17 + quad * 4 + r]) * linv[r];
        if (do_diag) o += 0.3f * diagv[b * 32 + irow] * cs;
        AOT[((size_t)b * NPIX + irow) * C + dch] = f2bf(o);
      }
    }
  }
}

// ---------------------------------------------------------------------------
// K3: gate. One block per (b, row h); 16 distinct gate values per row.
// ---------------------------------------------------------------------------
__global__ __launch_bounds__(256) void k_gate(
    const float* __restrict__ x,
    const float* __restrict__ wg1, const float* __restrict__ bg1,
    const float* __restrict__ wg2, const float* __restrict__ bg2,
    float* __restrict__ gate) {
  const int h = blockIdx.x, b = blockIdx.y, tid = threadIdx.x;
  __shared__ float pl[16 * 257];
  __shared__ float gl[16 * 65];

  {
    const int c = tid;
    const float* row = x + ((size_t)(b * C + c) * NPIX + h * 32);
    float v[32];
#pragma unroll
    for (int m = 0; m < 32; ++m) v[m] = row[m];
#pragma unroll
    for (int k = 0; k < 16; ++k) pl[k * 257 + c] = fabsf(v[k] - v[31 - k]);
  }
  __syncthreads();

  const int o16 = tid >> 4, k = tid & 15;
#pragma unroll 1
  for (int p = 0; p < 4; ++p) {
    const int o = p * 16 + o16;
    const float* wr = wg1 + o * C;
    float a0 = 0.f, a1 = 0.f, a2 = 0.f, a3 = 0.f;
#pragma unroll 4
    for (int c = 0; c < C; c += 4) {
      a0 += wr[c]     * pl[k * 257 + c];
      a1 += wr[c + 1] * pl[k * 257 + c + 1];
      a2 += wr[c + 2] * pl[k * 257 + c + 2];
      a3 += wr[c + 3] * pl[k * 257 + c + 3];
    }
    float a = bg1[o] + ((a0 + a1) + (a2 + a3));
    gl[k * 65 + o] = 0.5f * a * (1.f + erff(a * 0.70710678118654752f));
  }
  __syncthreads();

  if (tid < 16) {
    float s = bg2[0];
    for (int o = 0; o < 64; ++o)
      s += wg2[o] * gl[tid * 65 + o];
    gate[(b * 32 + h) * 16 + tid] = 1.f / (1.f + expf(-s));
  }
}

// ---------------------------------------------------------------------------
// K4: output GEMM via MFMA, gate+bias fused. out fp32 [b][o][pix].
// ---------------------------------------------------------------------------
__global__ __launch_bounds__(256) void k_out_mfma(
    const u16* __restrict__ AOT, const u16* __restrict__ WO,
    const float* __restrict__ bout, const float* __restrict__ gate,
    float* __restrict__ out) {
  const int ob = blockIdx.x, pb = blockIdx.y, b = blockIdx.z;
  const int wv = threadIdx.x >> 6, lane = threadIdx.x & 63;
  const int quad = lane >> 4, l15 = lane & 15;
  const int o0 = ob * 64 + wv * 16;
  const int pix0 = pb * 128;

  const u16* arow = WO + (size_t)(o0 + l15) * C;
  bf16x8 af[8];
#pragma unroll
  for (int kc = 0; kc < 8; ++kc)
    af[kc] = *(const bf16x8*)(arow + kc * 32 + quad * 8);

  const u16* ab = AOT + (size_t)(b * NPIX + pix0) * C;
  f32x4 acc[8];
#pragma unroll
  for (int nt = 0; nt < 8; ++nt) acc[nt] = (f32x4){0.f, 0.f, 0.f, 0.f};

  for (int kc = 0; kc < 8; ++kc) {
#pragma unroll
    for (int nt = 0; nt < 8; ++nt) {
      bf16x8 bfr = *(const bf16x8*)(ab + (size_t)(nt * 16 + l15) * C +
                                    kc * 32 + quad * 8);
      acc[nt] = __builtin_amdgcn_mfma_f32_16x16x32_bf16(af[kc], bfr, acc[nt], 0, 0, 0);
    }
  }

#pragma unroll
  for (int nt = 0; nt < 8; ++nt) {
    const int pix = pix0 + nt * 16 + l15;
    const float gf = 1.f + gate[(b * 32 + (pix >> 5)) * 16 + ((pix & 31) >> 1)];
#pragma unroll
    for (int r = 0; r < 4; ++r) {
      const int o = o0 + 4 * quad + r;
      out[((size_t)b * C + o) * NPIX + pix] = acc[nt][r] * gf + bout[o];
    }
  }
}

// ---------------------------------------------------------------------------
extern "C" void kernel_launch(void* const* d_in, const int* in_sizes, int n_in,
                              void* d_out, int out_size, void* d_ws, size_t ws_size,
                              hipStream_t stream) {
  const float* x    = (const float*)d_in[0];
  const float* wqkv = (const float*)d_in[1];
  const float* wout = (const float*)d_in[2];
  const float* bout = (const float*)d_in[3];
  const float* wg1  = (const float*)d_in[4];
  const float* bg1  = (const float*)d_in[5];
  const float* wg2  = (const float*)d_in[6];
  const float* bg2  = (const float*)d_in[7];
  float* out = (float*)d_out;

  const size_t SZ = (size_t)B * HEADS * NPIX * D;   // 2,097,152
  u16* XT = (u16*)d_ws;
  u16* WQ = XT + SZ;
  u16* WO = WQ + (size_t)OC * C;
  u16* Q  = WO + (size_t)C * C;
  u16* Kq = Q + SZ;
  u16* VT = Kq + SZ;
  float* DIAG = (float*)(VT + SZ);
  float* COL  = DIAG + 256;
  float* GATE = COL + 2048;
  u16* AOT = XT;   // alias: XT dead after k_qkv_mfma

  hipLaunchKernelGGL(k_prep, dim3(768), dim3(256), 0, stream,
                     x, wqkv, wout, WQ, WO, XT);
  hipLaunchKernelGGL(k_qkv_mfma, dim3(12, 8, B), dim3(256), 0, stream,
                     XT, WQ, Q, Kq, VT);
  hipLaunchKernelGGL(k_red, dim3(72), dim3(256), 0, stream,
                     (const uint*)Q, (const uint*)Kq, VT, DIAG, COL);
  hipLaunchKernelGGL(k_attn, dim3(32, 64), dim3(256), 0, stream,
                     Q, Kq, VT, DIAG, COL, AOT);
  hipLaunchKernelGGL(k_gate, dim3(32, B), dim3(256), 0, stream,
                     x, wg1, bg1, wg2, bg2, GATE);
  hipLaunchKernelGGL(k_out_mfma, dim3(4, 8, B), dim3(256), 0, stream,
                     AOT, WO, bout, GATE, out);
}